// Round 5
// baseline (618.506 us; speedup 1.0000x reference)
//
#include <hip/hip_runtime.h>

#define Bn 8
#define Hn 512
#define Wn 512
#define Cn 16

typedef float fx4 __attribute__((ext_vector_type(4)));

__device__ __forceinline__ float dgf(float g) { return 2.0f / (1.0f + __expf(-g)); }

// ---------------- fused grid kernel ----------------
// blocks 0..63     : y-channel column scans (b, 64-col tile), 8 waves x 64 rows
// blocks 64..4159  : x-channel row scans, one (b,h) row per block
__global__ __launch_bounds__(512) void grid_kernel(const float* __restrict__ defgrad,
                                                   float* __restrict__ grid_norm,
                                                   float* __restrict__ grid_inv) {
    const int wave = threadIdx.x >> 6;
    const int lane = threadIdx.x & 63;

    if (blockIdx.x < 64) {
        // ---- column scan over H for y channel ----
        __shared__ float partial[8][64];
        const int b  = blockIdx.x >> 3;
        const int w0 = (blockIdx.x & 7) * 64;
        const int w  = w0 + lane;
        const long cbase = ((long)b * Hn) * Wn + w;   // pixel index at (b,0,w)

        float e0 = dgf(defgrad[cbase * 2 + 1]);       // first element of column
        float sum = 0.f;
        #pragma unroll 8
        for (int i = 0; i < 64; ++i) {
            int h = (wave << 6) + i;
            sum += dgf(defgrad[(cbase + (long)h * Wn) * 2 + 1]);
        }
        partial[wave][lane] = sum;
        __syncthreads();
        float off = 0.f, tot = 0.f;
        #pragma unroll
        for (int j = 0; j < 8; ++j) {
            float p = partial[j][lane];
            if (j < wave) off += p;
            tot += p;
        }
        float denom = tot - e0;
        float run = off;
        #pragma unroll 8
        for (int i = 0; i < 64; ++i) {
            int h = (wave << 6) + i;
            long pidx = cbase + (long)h * Wn;
            run += dgf(defgrad[pidx * 2 + 1]);
            // reference: ratio is exactly 1.0 at h=511 -> norm exactly 511
            float norm = (h == Hn - 1) ? 511.0f : 511.0f * ((run - e0) / denom);
            grid_norm[pidx * 2 + 1] = norm;
            grid_inv[pidx * 2 + 1]  = 2.0f * (float)h - norm;
        }
    } else {
        // ---- row scan over W for x channel ----
        __shared__ float wsum[8];
        __shared__ float s0sh;
        const int row = blockIdx.x - 64;              // b*H + h
        const int t   = threadIdx.x;                  // w
        const long base = (long)row * Wn;

        float v = dgf(defgrad[(base + t) * 2]);
        float x = v;
        #pragma unroll
        for (int o = 1; o < 64; o <<= 1) {
            float n = __shfl_up(x, o, 64);
            x += (lane >= o) ? n : 0.0f;
        }
        if (lane == 63) wsum[wave] = x;
        if (t == 0)     s0sh = v;
        __syncthreads();
        float pre = 0.f, tot = 0.f;
        #pragma unroll
        for (int j = 0; j < 8; ++j) {
            float p = wsum[j];
            if (j < wave) pre += p;
            tot += p;
        }
        float scan = x + pre;
        float s0   = s0sh;
        float norm = (t == Wn - 1) ? 511.0f : 511.0f * ((scan - s0) / (tot - s0));
        long o = (base + t) * 2;
        grid_norm[o] = norm;
        grid_inv[o]  = 2.0f * (float)t - norm;
    }
}

// ---------------- bilinear resample: 1 thread per pixel, 16 channels ----------------
__global__ __launch_bounds__(256) void resample_kernel(const float* __restrict__ im,
                                                       const float* __restrict__ grid,
                                                       float* __restrict__ out) {
    const int pix = blockIdx.x * 256 + threadIdx.x;   // 2M pixels
    const int bi  = pix >> 18;                        // / (512*512)

    float2 g = *(const float2*)&grid[(long)pix * 2];
    float x = g.x, y = g.y;
    int x0 = (int)floorf(x);
    int y0 = (int)floorf(y);
    int x1 = x0 + 1, y1 = y0 + 1;
    x0 = min(max(x0, 0), Wn - 1);
    x1 = min(max(x1, 0), Wn - 1);
    y0 = min(max(y0, 0), Hn - 1);
    y1 = min(max(y1, 0), Hn - 1);
    // weights from CLIPPED coords (reference semantics: exact-edge -> all-zero weights)
    float x0f = (float)x0, x1f = (float)x1, y0f = (float)y0, y1f = (float)y1;
    float wa = (x1f - x) * (y1f - y);
    float wb = (x1f - x) * (y - y0f);
    float wc = (x - x0f) * (y1f - y);
    float wd = (x - x0f) * (y - y0f);

    const float* base = im + ((long)bi << 22);        // bi * 512*512*16
    const fx4* A = (const fx4*)(base + (((long)(y0 << 9) + x0) << 4));
    const fx4* Bp= (const fx4*)(base + (((long)(y1 << 9) + x0) << 4));
    const fx4* Cp= (const fx4*)(base + (((long)(y0 << 9) + x1) << 4));
    const fx4* Dp= (const fx4*)(base + (((long)(y1 << 9) + x1) << 4));
    fx4* O = (fx4*)(out + ((long)pix << 4));

    #pragma unroll
    for (int c = 0; c < 4; ++c) {
        fx4 a = A[c], b = Bp[c], cc = Cp[c], d = Dp[c];
        fx4 r = wa * a + wb * b + wc * cc + wd * d;
        __builtin_nontemporal_store(r, &O[c]);
    }
}

extern "C" void kernel_launch(void* const* d_in, const int* in_sizes, int n_in,
                              void* d_out, int out_size, void* d_ws, size_t ws_size,
                              hipStream_t stream) {
    const float* mov     = (const float*)d_in[0];
    const float* defgrad = (const float*)d_in[2];
    float* out = (float*)d_out;

    const long N_img  = (long)Bn * Hn * Wn * Cn;   // 33554432
    const long N_grid = (long)Bn * Hn * Wn * 2;    // 4194304
    float* mov_def   = out;
    float* ref_def   = out + N_img;
    float* grid_norm = out + 2 * N_img;
    float* grid_inv  = out + 2 * N_img + N_grid;

    grid_kernel<<<dim3(64 + Bn * Hn), dim3(512), 0, stream>>>(defgrad, grid_norm, grid_inv);

    const int npix = Bn * Hn * Wn;                 // 2M pixels, 1 thread each
    resample_kernel<<<dim3(npix / 256), dim3(256), 0, stream>>>(mov, grid_norm, mov_def);
    resample_kernel<<<dim3(npix / 256), dim3(256), 0, stream>>>(mov_def, grid_inv, ref_def);
}

// Round 6
// 517.485 us; speedup vs baseline: 1.1952x; 1.1952x over previous
//
#include <hip/hip_runtime.h>

#define Bn 8
#define Hn 512
#define Wn 512
#define Cn 16

typedef float fx4 __attribute__((ext_vector_type(4)));

__device__ __forceinline__ float dgf(float g) { return 2.0f / (1.0f + __expf(-g)); }

// ---------------- fused grid kernel (bitwise-identical to R5) ----------------
// blocks 0..63     : y-channel column scans (b, 64-col tile), 8 waves x 64 rows
// blocks 64..4159  : x-channel row scans, one (b,h) row per block
__global__ __launch_bounds__(512) void grid_kernel(const float* __restrict__ defgrad,
                                                   float* __restrict__ grid_norm,
                                                   float* __restrict__ grid_inv) {
    const int wave = threadIdx.x >> 6;
    const int lane = threadIdx.x & 63;

    if (blockIdx.x < 64) {
        // ---- column scan over H for y channel ----
        __shared__ float partial[8][64];
        const int b  = blockIdx.x >> 3;
        const int w0 = (blockIdx.x & 7) * 64;
        const int w  = w0 + lane;
        const long cbase = ((long)b * Hn) * Wn + w;   // pixel index at (b,0,w)

        float e0 = dgf(defgrad[cbase * 2 + 1]);       // first element of column
        float sum = 0.f;
        #pragma unroll 8
        for (int i = 0; i < 64; ++i) {
            int h = (wave << 6) + i;
            sum += dgf(defgrad[(cbase + (long)h * Wn) * 2 + 1]);
        }
        partial[wave][lane] = sum;
        __syncthreads();
        float off = 0.f, tot = 0.f;
        #pragma unroll
        for (int j = 0; j < 8; ++j) {
            float p = partial[j][lane];
            if (j < wave) off += p;
            tot += p;
        }
        float denom = tot - e0;
        float run = off;
        #pragma unroll 8
        for (int i = 0; i < 64; ++i) {
            int h = (wave << 6) + i;
            long pidx = cbase + (long)h * Wn;
            run += dgf(defgrad[pidx * 2 + 1]);
            // reference: ratio is exactly 1.0 at h=511 -> norm exactly 511
            float norm = (h == Hn - 1) ? 511.0f : 511.0f * ((run - e0) / denom);
            grid_norm[pidx * 2 + 1] = norm;
            grid_inv[pidx * 2 + 1]  = 2.0f * (float)h - norm;
        }
    } else {
        // ---- row scan over W for x channel ----
        __shared__ float wsum[8];
        __shared__ float s0sh;
        const int row = blockIdx.x - 64;              // b*H + h
        const int t   = threadIdx.x;                  // w
        const long base = (long)row * Wn;

        float v = dgf(defgrad[(base + t) * 2]);
        float x = v;
        #pragma unroll
        for (int o = 1; o < 64; o <<= 1) {
            float n = __shfl_up(x, o, 64);
            x += (lane >= o) ? n : 0.0f;
        }
        if (lane == 63) wsum[wave] = x;
        if (t == 0)     s0sh = v;
        __syncthreads();
        float pre = 0.f, tot = 0.f;
        #pragma unroll
        for (int j = 0; j < 8; ++j) {
            float p = wsum[j];
            if (j < wave) pre += p;
            tot += p;
        }
        float scan = x + pre;
        float s0   = s0sh;
        float norm = (t == Wn - 1) ? 511.0f : 511.0f * ((scan - s0) / (tot - s0));
        long o = (base + t) * 2;
        grid_norm[o] = norm;
        grid_inv[o]  = 2.0f * (float)t - norm;
    }
}

// ---------------- bilinear resample ----------------
// 4 threads per pixel (one 16B channel-group each, lane-contiguous = coalesced
// ~1KB wave transactions per corner), 2 pixels per thread (8 independent 16B
// gathers in flight). Block of 256 threads covers 128 consecutive pixels.
__global__ __launch_bounds__(256) void resample_kernel(const float* __restrict__ im,
                                                       const float* __restrict__ grid,
                                                       float* __restrict__ out) {
    const int tid = threadIdx.x;
    const int cg  = tid & 3;                    // channel group 0..3
    const int q   = tid >> 2;                   // 0..63
    const long p0 = (long)blockIdx.x * 128 + q; // first pixel
    const long p1 = p0 + 64;                    // second pixel

    float2 g0 = *(const float2*)&grid[p0 * 2];
    float2 g1 = *(const float2*)&grid[p1 * 2];

    // --- pixel 0 addresses ---
    int x0a = (int)floorf(g0.x), y0a = (int)floorf(g0.y);
    int x1a = min(max(x0a + 1, 0), Wn - 1), y1a = min(max(y0a + 1, 0), Hn - 1);
    x0a = min(max(x0a, 0), Wn - 1);  y0a = min(max(y0a, 0), Hn - 1);
    // --- pixel 1 addresses ---
    int x0b = (int)floorf(g1.x), y0b = (int)floorf(g1.y);
    int x1b = min(max(x0b + 1, 0), Wn - 1), y1b = min(max(y0b + 1, 0), Hn - 1);
    x0b = min(max(x0b, 0), Wn - 1);  y0b = min(max(y0b, 0), Hn - 1);

    const float* base0 = im + ((p0 >> 18) << 22) + cg * 4;   // batch base + channel offset
    const float* base1 = im + ((p1 >> 18) << 22) + cg * 4;

    // issue all 8 independent 16B gathers
    fx4 A0 = *(const fx4*)(base0 + (((long)(y0a << 9) + x0a) << 4));
    fx4 B0 = *(const fx4*)(base0 + (((long)(y1a << 9) + x0a) << 4));
    fx4 C0 = *(const fx4*)(base0 + (((long)(y0a << 9) + x1a) << 4));
    fx4 D0 = *(const fx4*)(base0 + (((long)(y1a << 9) + x1a) << 4));
    fx4 A1 = *(const fx4*)(base1 + (((long)(y0b << 9) + x0b) << 4));
    fx4 B1 = *(const fx4*)(base1 + (((long)(y1b << 9) + x0b) << 4));
    fx4 C1 = *(const fx4*)(base1 + (((long)(y0b << 9) + x1b) << 4));
    fx4 D1 = *(const fx4*)(base1 + (((long)(y1b << 9) + x1b) << 4));

    // weights from CLIPPED coords (reference semantics: exact-edge -> zero weights)
    float wa0 = ((float)x1a - g0.x) * ((float)y1a - g0.y);
    float wb0 = ((float)x1a - g0.x) * (g0.y - (float)y0a);
    float wc0 = (g0.x - (float)x0a) * ((float)y1a - g0.y);
    float wd0 = (g0.x - (float)x0a) * (g0.y - (float)y0a);
    float wa1 = ((float)x1b - g1.x) * ((float)y1b - g1.y);
    float wb1 = ((float)x1b - g1.x) * (g1.y - (float)y0b);
    float wc1 = (g1.x - (float)x0b) * ((float)y1b - g1.y);
    float wd1 = (g1.x - (float)x0b) * (g1.y - (float)y0b);

    fx4 r0 = wa0 * A0 + wb0 * B0 + wc0 * C0 + wd0 * D0;
    fx4 r1 = wa1 * A1 + wb1 * B1 + wc1 * C1 + wd1 * D1;

    __builtin_nontemporal_store(r0, (fx4*)(out + (p0 << 4) + cg * 4));
    __builtin_nontemporal_store(r1, (fx4*)(out + (p1 << 4) + cg * 4));
}

extern "C" void kernel_launch(void* const* d_in, const int* in_sizes, int n_in,
                              void* d_out, int out_size, void* d_ws, size_t ws_size,
                              hipStream_t stream) {
    const float* mov     = (const float*)d_in[0];
    const float* defgrad = (const float*)d_in[2];
    float* out = (float*)d_out;

    const long N_img  = (long)Bn * Hn * Wn * Cn;   // 33554432
    const long N_grid = (long)Bn * Hn * Wn * 2;    // 4194304
    float* mov_def   = out;
    float* ref_def   = out + N_img;
    float* grid_norm = out + 2 * N_img;
    float* grid_inv  = out + 2 * N_img + N_grid;

    grid_kernel<<<dim3(64 + Bn * Hn), dim3(512), 0, stream>>>(defgrad, grid_norm, grid_inv);

    const int npix = Bn * Hn * Wn;                 // 2M pixels
    resample_kernel<<<dim3(npix / 128), dim3(256), 0, stream>>>(mov, grid_norm, mov_def);
    resample_kernel<<<dim3(npix / 128), dim3(256), 0, stream>>>(mov_def, grid_inv, ref_def);
}